// Round 1
// baseline (509.309 us; speedup 1.0000x reference)
//
#include <hip/hip_runtime.h>

#define NDIM 32
#define EDIM 16
#define NHID 64
#define NIN1 144

// ---------------------------------------------------------------------------
// Scatter: per-edge atomic accumulation.
//   efsum[d][0:16] += ef[e]        (k in [0,16))
//   hsum [d][0:64] += h[src[e]]    (k in [16,80))
//   deg  [d]       += 1            (k == 0)
// One thread per (edge, k), k in [0,80). Consecutive threads hit consecutive
// addresses of the same edge row -> coalesced reads, same-cacheline atomics.
// ---------------------------------------------------------------------------
__global__ __launch_bounds__(256) void sse_scatter(
    const float* __restrict__ h, const float* __restrict__ ef,
    const int* __restrict__ src, const int* __restrict__ dst,
    float* __restrict__ efsum, float* __restrict__ hsum,
    float* __restrict__ deg, int E) {
  long long idx = (long long)blockIdx.x * 256 + threadIdx.x;
  long long total = (long long)E * 80;
  if (idx >= total) return;
  int e = (int)(idx / 80);
  int k = (int)(idx - (long long)e * 80);
  int d = dst[e];
  if (k < EDIM) {
    atomicAdd(&efsum[d * EDIM + k], ef[e * EDIM + k]);
    if (k == 0) atomicAdd(&deg[d], 1.0f);
  } else {
    int s = src[e];
    int j = k - EDIM;
    atomicAdd(&hsum[d * NHID + j], h[s * NHID + j]);
  }
}

// ---------------------------------------------------------------------------
// Node update: z = [nf | deg*nf | efsum | hsum]  (144)
//   out = relu(z @ W1^T) @ W2^T, masked by deg>0 (else passthrough h).
// Block = 256 threads = 4 nodes x 64 lanes. Weights transposed into LDS:
//   w1t[k][r] = W1[r][k]  -> lane r reads w1t[k][lane]: stride-1 across
//   lanes = 2 lanes/bank = free. z/a reads are wave-uniform broadcasts.
// Grid-stride over node groups so each block stages weights exactly once.
// ---------------------------------------------------------------------------
__global__ __launch_bounds__(256) void sse_node(
    const float* __restrict__ h, const float* __restrict__ nf,
    const float* __restrict__ efsum, const float* __restrict__ hsum,
    const float* __restrict__ deg, const float* __restrict__ W1,
    const float* __restrict__ W2, float* __restrict__ out,
    int N, int ngroups) {
  __shared__ float w1t[NIN1][NHID];   // 36864 B
  __shared__ float w2t[NHID][NHID];   // 16384 B
  __shared__ float zsh[4][NIN1];      //  2304 B
  __shared__ float ash[4][NHID];      //  1024 B

  int tid = threadIdx.x;
  for (int i = tid; i < NHID * NIN1; i += 256) {
    int r = i / NIN1;
    int k = i - r * NIN1;
    w1t[k][r] = W1[i];
  }
  for (int i = tid; i < NHID * NHID; i += 256) {
    w2t[i & (NHID - 1)][i >> 6] = W2[i];
  }
  __syncthreads();

  int lane = tid & 63;   // output row r / feature lane
  int sub  = tid >> 6;   // node within the 4-node group (wave-uniform)

  for (int g = blockIdx.x; g < ngroups; g += gridDim.x) {
    int node = g * 4 + sub;
    bool valid = node < N;
    float dg = 0.0f;
    if (valid) {
      dg = deg[node];
      // z[0:32]=nf, z[32:64]=deg*nf, z[64:80]=efsum, z[80:144]=hsum
      float v0 = (lane < NDIM) ? nf[node * NDIM + lane]
                               : dg * nf[node * NDIM + (lane - NDIM)];
      zsh[sub][lane] = v0;
      int k2 = lane + 64;
      float v1 = (k2 < 80) ? efsum[node * EDIM + (k2 - 64)]
                           : hsum[node * NHID + (k2 - 80)];
      zsh[sub][k2] = v1;
      if (lane < 16) zsh[sub][128 + lane] = hsum[node * NHID + 48 + lane];
    }
    __syncthreads();

    // layer 1: acc = dot(W1[lane,:], z) with 4 partial sums for ILP
    float p0 = 0.f, p1 = 0.f, p2 = 0.f, p3 = 0.f;
#pragma unroll
    for (int k = 0; k < NIN1; k += 4) {
      p0 = fmaf(w1t[k + 0][lane], zsh[sub][k + 0], p0);
      p1 = fmaf(w1t[k + 1][lane], zsh[sub][k + 1], p1);
      p2 = fmaf(w1t[k + 2][lane], zsh[sub][k + 2], p2);
      p3 = fmaf(w1t[k + 3][lane], zsh[sub][k + 3], p3);
    }
    ash[sub][lane] = fmaxf((p0 + p1) + (p2 + p3), 0.0f);
    __syncthreads();

    // layer 2: o = dot(W2[lane,:], a)
    float q0 = 0.f, q1 = 0.f, q2 = 0.f, q3 = 0.f;
#pragma unroll
    for (int k = 0; k < NHID; k += 4) {
      q0 = fmaf(w2t[k + 0][lane], ash[sub][k + 0], q0);
      q1 = fmaf(w2t[k + 1][lane], ash[sub][k + 1], q1);
      q2 = fmaf(w2t[k + 2][lane], ash[sub][k + 2], q2);
      q3 = fmaf(w2t[k + 3][lane], ash[sub][k + 3], q3);
    }
    if (valid) {
      float o = (q0 + q1) + (q2 + q3);
      out[(long long)node * NHID + lane] =
          (dg > 0.0f) ? o : h[(long long)node * NHID + lane];
    }
    __syncthreads();  // zsh/ash reused next iteration
  }
}

extern "C" void kernel_launch(void* const* d_in, const int* in_sizes, int n_in,
                              void* d_out, int out_size, void* d_ws, size_t ws_size,
                              hipStream_t stream) {
  const float* h  = (const float*)d_in[0];
  const float* nf = (const float*)d_in[1];
  const float* ef = (const float*)d_in[2];
  const int*   src = (const int*)d_in[3];
  const int*   dst = (const int*)d_in[4];
  const float* W1 = (const float*)d_in[5];
  const float* W2 = (const float*)d_in[6];
  float* out = (float*)d_out;

  int N = in_sizes[0] / NHID;   // h is [N, 64]
  int E = in_sizes[3];          // src is [E]

  // ws layout: efsum [N*16] | hsum [N*64] | deg [N]
  float* efsum = (float*)d_ws;
  float* hsum  = efsum + (size_t)N * EDIM;
  float* dega  = hsum + (size_t)N * NHID;
  size_t zero_bytes = (size_t)N * (EDIM + NHID + 1) * sizeof(float);
  hipMemsetAsync(d_ws, 0, zero_bytes, stream);

  long long total = (long long)E * 80;
  int sblocks = (int)((total + 255) / 256);
  sse_scatter<<<sblocks, 256, 0, stream>>>(h, ef, src, dst, efsum, hsum, dega, E);

  int ngroups = (N + 3) / 4;
  int nblocks = ngroups < 512 ? ngroups : 512;
  sse_node<<<nblocks, 256, 0, stream>>>(h, nf, efsum, hsum, dega, W1, W2, out,
                                        N, ngroups);
}

// Round 2
// 461.410 us; speedup vs baseline: 1.1038x; 1.1038x over previous
//
#include <hip/hip_runtime.h>

#define NDIM 32
#define EDIM 16
#define NHID 64
#define NIN1 144
#define SCAN_T 1024

// ---------------------------------------------------------------------------
// 1) Histogram of dst -> counts[N]
// ---------------------------------------------------------------------------
__global__ __launch_bounds__(256) void sse_hist(
    const int* __restrict__ dst, int* __restrict__ counts, int E) {
  int e = blockIdx.x * 256 + threadIdx.x;
  if (e < E) atomicAdd(&counts[dst[e]], 1);
}

// ---------------------------------------------------------------------------
// 2) Exclusive prefix scan over counts -> starts[N+1], cursors[N] (copy).
//    Single block of 1024; each thread owns a contiguous chunk of ~49.
// ---------------------------------------------------------------------------
__global__ __launch_bounds__(SCAN_T) void sse_scan(
    const int* __restrict__ counts, int* __restrict__ starts,
    int* __restrict__ cursors, int N) {
  __shared__ int lsum[SCAN_T];
  int t = threadIdx.x;
  int chunk = (N + SCAN_T - 1) / SCAN_T;
  int lo = t * chunk, hi = min(lo + chunk, N);
  if (lo > N) lo = N;
  int s = 0;
  for (int i = lo; i < hi; ++i) s += counts[i];
  lsum[t] = s;
  __syncthreads();
  // Hillis-Steele inclusive scan
  for (int off = 1; off < SCAN_T; off <<= 1) {
    int v = (t >= off) ? lsum[t - off] : 0;
    __syncthreads();
    lsum[t] += v;
    __syncthreads();
  }
  int run = lsum[t] - s;  // exclusive prefix for this chunk
  for (int i = lo; i < hi; ++i) {
    starts[i] = run;
    cursors[i] = run;
    run += counts[i];
  }
  if (t == SCAN_T - 1) starts[N] = lsum[SCAN_T - 1];  // = E
}

// ---------------------------------------------------------------------------
// 3) Build sorted edge lists: for each edge, place (src, eid) at cursor[dst]++
// ---------------------------------------------------------------------------
__global__ __launch_bounds__(256) void sse_build(
    const int* __restrict__ src, const int* __restrict__ dst,
    int* __restrict__ cursors, int* __restrict__ ssrc,
    int* __restrict__ seid, int E) {
  int e = blockIdx.x * 256 + threadIdx.x;
  if (e >= E) return;
  int d = dst[e];
  int pos = atomicAdd(&cursors[d], 1);
  ssrc[pos] = src[e];
  seid[pos] = e;
}

// ---------------------------------------------------------------------------
// 4) Atomic-free gather: one wave per node walks its edge range.
//    lane = feature. hsum all 64 lanes; efsum lanes 0..15.
//    No LDS, tiny VGPR -> max occupancy hides the gather latency.
// ---------------------------------------------------------------------------
__global__ __launch_bounds__(256) void sse_gather(
    const float* __restrict__ h, const float* __restrict__ ef,
    const int* __restrict__ starts, const int* __restrict__ ssrc,
    const int* __restrict__ seid, float* __restrict__ efsum,
    float* __restrict__ hsum, int N) {
  int node = blockIdx.x * 4 + (threadIdx.x >> 6);
  int lane = threadIdx.x & 63;
  if (node >= N) return;
  int st = starts[node], en = starts[node + 1];
  float hs = 0.f, es = 0.f;
  int j = st;
  // unroll by 2 for independent outstanding gathers
  for (; j + 1 < en; j += 2) {
    int s0 = ssrc[j], s1 = ssrc[j + 1];
    float a0 = h[s0 * NHID + lane];
    float a1 = h[s1 * NHID + lane];
    hs += a0 + a1;
    if (lane < EDIM) {
      es += ef[seid[j] * EDIM + lane] + ef[seid[j + 1] * EDIM + lane];
    }
  }
  if (j < en) {
    hs += h[ssrc[j] * NHID + lane];
    if (lane < EDIM) es += ef[seid[j] * EDIM + lane];
  }
  hsum[node * NHID + lane] = hs;
  if (lane < EDIM) efsum[node * EDIM + lane] = es;
}

// ---------------------------------------------------------------------------
// 5) Node MLP: z = [nf | deg*nf | efsum | hsum] (144)
//    out = relu(z @ W1^T) @ W2^T, passthrough h where deg==0.
//    Weights in LDS as float4 [k4][lane]: lane-contiguous 16B -> conflict-free
//    ds_read_b128. z/a read as broadcast float4 (same addr all lanes).
// ---------------------------------------------------------------------------
__global__ __launch_bounds__(256) void sse_node(
    const float* __restrict__ h, const float* __restrict__ nf,
    const float* __restrict__ efsum, const float* __restrict__ hsum,
    const int* __restrict__ starts, const float* __restrict__ W1,
    const float* __restrict__ W2, float* __restrict__ out,
    int N, int ngroups) {
  __shared__ float4 w1v[NIN1 / 4][NHID];  // [36][64] = 36 KB
  __shared__ float4 w2v[NHID / 4][NHID];  // [16][64] = 16 KB
  __shared__ __align__(16) float zsh[4][NIN1];  // 2.3 KB
  __shared__ __align__(16) float ash[4][NHID];  // 1 KB

  int tid = threadIdx.x;
  for (int i = tid; i < 36 * NHID; i += 256) {
    int r = i / 36;
    int k4 = i - r * 36;
    w1v[k4][r] = *(const float4*)&W1[r * NIN1 + k4 * 4];
  }
  for (int i = tid; i < 16 * NHID; i += 256) {
    int r = i >> 4;
    int k4 = i & 15;
    w2v[k4][r] = *(const float4*)&W2[r * NHID + k4 * 4];
  }
  __syncthreads();

  int lane = tid & 63;  // output row / feature lane
  int sub = tid >> 6;   // node within group (wave-uniform)

  for (int g = blockIdx.x; g < ngroups; g += gridDim.x) {
    int node = g * 4 + sub;
    bool valid = node < N;
    int dgi = 0;
    if (valid) {
      int st = starts[node], en = starts[node + 1];
      dgi = en - st;
      float dg = (float)dgi;
      float v0 = (lane < NDIM) ? nf[node * NDIM + lane]
                               : dg * nf[node * NDIM + (lane - NDIM)];
      zsh[sub][lane] = v0;
      int k2 = lane + 64;
      float v1 = (k2 < 80) ? efsum[node * EDIM + (k2 - 64)]
                           : hsum[node * NHID + (k2 - 80)];
      zsh[sub][k2] = v1;
      if (lane < 16) zsh[sub][128 + lane] = hsum[node * NHID + 48 + lane];
    }
    __syncthreads();

    // layer 1: acc_r = dot(W1[lane,:], z)
    float4 p = make_float4(0.f, 0.f, 0.f, 0.f);
#pragma unroll 4
    for (int k4 = 0; k4 < NIN1 / 4; ++k4) {
      float4 w = w1v[k4][lane];
      float4 z = *(const float4*)&zsh[sub][k4 * 4];
      p.x = fmaf(w.x, z.x, p.x);
      p.y = fmaf(w.y, z.y, p.y);
      p.z = fmaf(w.z, z.z, p.z);
      p.w = fmaf(w.w, z.w, p.w);
    }
    ash[sub][lane] = fmaxf((p.x + p.y) + (p.z + p.w), 0.0f);
    __syncthreads();

    // layer 2
    float4 q = make_float4(0.f, 0.f, 0.f, 0.f);
#pragma unroll 4
    for (int k4 = 0; k4 < NHID / 4; ++k4) {
      float4 w = w2v[k4][lane];
      float4 a = *(const float4*)&ash[sub][k4 * 4];
      q.x = fmaf(w.x, a.x, q.x);
      q.y = fmaf(w.y, a.y, q.y);
      q.z = fmaf(w.z, a.z, q.z);
      q.w = fmaf(w.w, a.w, q.w);
    }
    if (valid) {
      if (dgi > 0) {
        out[(long long)node * NHID + lane] = (q.x + q.y) + (q.z + q.w);
      } else {
        out[(long long)node * NHID + lane] = h[(long long)node * NHID + lane];
      }
    }
    __syncthreads();  // zsh/ash reused next iteration
  }
}

extern "C" void kernel_launch(void* const* d_in, const int* in_sizes, int n_in,
                              void* d_out, int out_size, void* d_ws, size_t ws_size,
                              hipStream_t stream) {
  const float* h  = (const float*)d_in[0];
  const float* nf = (const float*)d_in[1];
  const float* ef = (const float*)d_in[2];
  const int*   src = (const int*)d_in[3];
  const int*   dst = (const int*)d_in[4];
  const float* W1 = (const float*)d_in[5];
  const float* W2 = (const float*)d_in[6];
  float* out = (float*)d_out;

  int N = in_sizes[0] / NHID;  // h is [N, 64]
  int E = in_sizes[3];         // src is [E]

  // ws layout (all 4-byte elems):
  // counts[N] | starts[N+1] | cursors[N] | ssrc[E] | seid[E] |
  // efsum[N*16] | hsum[N*64]   -> ~23 MB total
  int* counts  = (int*)d_ws;
  int* starts  = counts + N;
  int* cursors = starts + N + 1;
  int* ssrc    = cursors + N;
  int* seid    = ssrc + E;
  float* efsum = (float*)(seid + E);
  float* hsum  = efsum + (size_t)N * EDIM;

  hipMemsetAsync(counts, 0, (size_t)N * sizeof(int), stream);

  int eblocks = (E + 255) / 256;
  sse_hist<<<eblocks, 256, 0, stream>>>(dst, counts, E);
  sse_scan<<<1, SCAN_T, 0, stream>>>(counts, starts, cursors, N);
  sse_build<<<eblocks, 256, 0, stream>>>(src, dst, cursors, ssrc, seid, E);

  int gblocks = (N + 3) / 4;
  sse_gather<<<gblocks, 256, 0, stream>>>(h, ef, starts, ssrc, seid,
                                          efsum, hsum, N);

  int ngroups = (N + 3) / 4;
  int nblocks = ngroups < 512 ? ngroups : 512;
  sse_node<<<nblocks, 256, 0, stream>>>(h, nf, efsum, hsum, starts, W1, W2,
                                        out, N, ngroups);
}

// Round 3
// 313.620 us; speedup vs baseline: 1.6240x; 1.4712x over previous
//
#include <hip/hip_runtime.h>

#define NDIM 32
#define EDIM 16
#define NHID 64
#define NIN1 144
#define SCHUNK 1024  // counts per scan block
#define SPT 4        // counts per thread (256 threads/block)

// ---------------------------------------------------------------------------
// 1) Histogram of dst -> counts[N]
// ---------------------------------------------------------------------------
__global__ __launch_bounds__(256) void sse_hist(
    const int* __restrict__ dst, int* __restrict__ counts, int E) {
  int e = blockIdx.x * 256 + threadIdx.x;
  if (e < E) atomicAdd(&counts[dst[e]], 1);
}

// ---------------------------------------------------------------------------
// 2a) Per-block partial sums over 1024-count chunks.
// ---------------------------------------------------------------------------
__global__ __launch_bounds__(256) void sse_scan_part(
    const int* __restrict__ counts, int* __restrict__ bsum, int N) {
  __shared__ int ws[4];
  int t = threadIdx.x;
  int base = blockIdx.x * SCHUNK + t * SPT;
  int s = 0;
#pragma unroll
  for (int i = 0; i < SPT; ++i) {
    int idx = base + i;
    if (idx < N) s += counts[idx];
  }
  int v = s;
#pragma unroll
  for (int off = 1; off < 64; off <<= 1) v += __shfl_xor(v, off, 64);
  if ((t & 63) == 0) ws[t >> 6] = v;
  __syncthreads();
  if (t == 0) bsum[blockIdx.x] = ws[0] + ws[1] + ws[2] + ws[3];
}

// ---------------------------------------------------------------------------
// 2b) Exclusive scan of <=64 block sums in one wave; also writes starts[N]=E.
// ---------------------------------------------------------------------------
__global__ __launch_bounds__(64) void sse_scan_top(
    const int* __restrict__ bsum, int* __restrict__ boff, int nb,
    int* __restrict__ startsN) {
  int t = threadIdx.x;
  int v = (t < nb) ? bsum[t] : 0;
  int incl = v;
#pragma unroll
  for (int off = 1; off < 64; off <<= 1) {
    int u = __shfl_up(incl, off, 64);
    if (t >= off) incl += u;
  }
  if (t < nb) boff[t] = incl - v;
  if (t == 63) *startsN = incl;  // total = E
}

// ---------------------------------------------------------------------------
// 2c) Final: re-scan each chunk, add block offset, emit starts & cursors.
// ---------------------------------------------------------------------------
__global__ __launch_bounds__(256) void sse_scan_final(
    const int* __restrict__ counts, const int* __restrict__ boff,
    int* __restrict__ starts, int* __restrict__ cursors, int N) {
  __shared__ int ws[4];
  int t = threadIdx.x;
  int lane = t & 63, w = t >> 6;
  int base = blockIdx.x * SCHUNK + t * SPT;
  int c[SPT];
  int s = 0;
#pragma unroll
  for (int i = 0; i < SPT; ++i) {
    int idx = base + i;
    c[i] = (idx < N) ? counts[idx] : 0;
    s += c[i];
  }
  int incl = s;
#pragma unroll
  for (int off = 1; off < 64; off <<= 1) {
    int u = __shfl_up(incl, off, 64);
    if (lane >= off) incl += u;
  }
  if (lane == 63) ws[w] = incl;
  __syncthreads();
  int woff = 0;
#pragma unroll
  for (int j = 0; j < 4; ++j)
    if (j < w) woff += ws[j];
  int run = boff[blockIdx.x] + woff + (incl - s);
#pragma unroll
  for (int i = 0; i < SPT; ++i) {
    int idx = base + i;
    if (idx < N) {
      starts[idx] = run;
      cursors[idx] = run;
      run += c[i];
    }
  }
}

// ---------------------------------------------------------------------------
// 3) Build sorted edge lists: place (src, eid) at cursor[dst]++
// ---------------------------------------------------------------------------
__global__ __launch_bounds__(256) void sse_build(
    const int* __restrict__ src, const int* __restrict__ dst,
    int* __restrict__ cursors, int* __restrict__ ssrc,
    int* __restrict__ seid, int E) {
  int e = blockIdx.x * 256 + threadIdx.x;
  if (e >= E) return;
  int d = dst[e];
  int pos = atomicAdd(&cursors[d], 1);
  ssrc[pos] = src[e];
  seid[pos] = e;
}

// ---------------------------------------------------------------------------
// 4) Atomic-free gather: one wave per node walks its edge range (unroll 4).
// ---------------------------------------------------------------------------
__global__ __launch_bounds__(256) void sse_gather(
    const float* __restrict__ h, const float* __restrict__ ef,
    const int* __restrict__ starts, const int* __restrict__ ssrc,
    const int* __restrict__ seid, float* __restrict__ efsum,
    float* __restrict__ hsum, int N) {
  int node = blockIdx.x * 4 + (threadIdx.x >> 6);
  int lane = threadIdx.x & 63;
  if (node >= N) return;
  int st = starts[node], en = starts[node + 1];
  float hs = 0.f, es = 0.f;
  int j = st;
  for (; j + 3 < en; j += 4) {
    int s0 = ssrc[j], s1 = ssrc[j + 1], s2 = ssrc[j + 2], s3 = ssrc[j + 3];
    float a0 = h[s0 * NHID + lane], a1 = h[s1 * NHID + lane];
    float a2 = h[s2 * NHID + lane], a3 = h[s3 * NHID + lane];
    hs += (a0 + a1) + (a2 + a3);
    if (lane < EDIM) {
      float b0 = ef[seid[j] * EDIM + lane], b1 = ef[seid[j + 1] * EDIM + lane];
      float b2 = ef[seid[j + 2] * EDIM + lane], b3 = ef[seid[j + 3] * EDIM + lane];
      es += (b0 + b1) + (b2 + b3);
    }
  }
  for (; j < en; ++j) {
    hs += h[ssrc[j] * NHID + lane];
    if (lane < EDIM) es += ef[seid[j] * EDIM + lane];
  }
  hsum[node * NHID + lane] = hs;
  if (lane < EDIM) efsum[node * EDIM + lane] = es;
}

// ---------------------------------------------------------------------------
// 5) Node MLP, 4 nodes per wave (16 per block-iter).
//    z = [nf | deg*nf | efsum | hsum] (144); out = relu(z@W1^T)@W2^T,
//    passthrough h where deg==0. Each weight ds_read_b128 amortized over
//    4 nodes -> weight LDS bytes/node cut 4x vs 1-node-per-wave.
// ---------------------------------------------------------------------------
__global__ __launch_bounds__(256) void sse_node(
    const float* __restrict__ h, const float* __restrict__ nf,
    const float* __restrict__ efsum, const float* __restrict__ hsum,
    const int* __restrict__ starts, const float* __restrict__ W1,
    const float* __restrict__ W2, float* __restrict__ out,
    int N, int ngroups) {
  __shared__ float4 w1v[NIN1 / 4][NHID];        // [36][64] = 36 KB
  __shared__ float4 w2v[NHID / 4][NHID];        // [16][64] = 16 KB
  __shared__ __align__(16) float zsh[16][NIN1]; // 9 KB
  __shared__ __align__(16) float ash[16][NHID]; // 4 KB

  int tid = threadIdx.x;
  for (int i = tid; i < 36 * NHID; i += 256) {
    int r = i / 36;
    int k4 = i - r * 36;
    w1v[k4][r] = *(const float4*)&W1[r * NIN1 + k4 * 4];
  }
  for (int i = tid; i < 16 * NHID; i += 256) {
    int r = i >> 4;
    int k4 = i & 15;
    w2v[k4][r] = *(const float4*)&W2[r * NHID + k4 * 4];
  }
  __syncthreads();

  int lane = tid & 63;  // output row / feature lane
  int w = tid >> 6;     // wave id; wave handles nodes g*16 + w*4 + {0..3}

  for (int g = blockIdx.x; g < ngroups; g += gridDim.x) {
    int nbase = g * 16 + w * 4;
    int degv[4];
    // stage z for this wave's 4 nodes
#pragma unroll
    for (int n = 0; n < 4; ++n) {
      int node = nbase + n;
      degv[n] = 0;
      if (node < N) {
        int st = starts[node], en = starts[node + 1];
        degv[n] = en - st;
        float dg = (float)degv[n];
        int zi = w * 4 + n;
        float v0 = (lane < NDIM) ? nf[node * NDIM + lane]
                                 : dg * nf[node * NDIM + (lane - NDIM)];
        zsh[zi][lane] = v0;
        int k2 = lane + 64;
        float v1 = (k2 < 80) ? efsum[node * EDIM + (k2 - 64)]
                             : hsum[node * NHID + (k2 - 80)];
        zsh[zi][k2] = v1;
        if (lane < 16) zsh[zi][128 + lane] = hsum[node * NHID + 48 + lane];
      }
    }
    __syncthreads();

    // layer 1: p[n] accumulates dot(W1[lane,:], z_n)
    float4 p[4];
#pragma unroll
    for (int n = 0; n < 4; ++n) p[n] = make_float4(0.f, 0.f, 0.f, 0.f);
#pragma unroll 6
    for (int k4 = 0; k4 < NIN1 / 4; ++k4) {
      float4 wv = w1v[k4][lane];
#pragma unroll
      for (int n = 0; n < 4; ++n) {
        float4 z = *(const float4*)&zsh[w * 4 + n][k4 * 4];
        p[n].x = fmaf(wv.x, z.x, p[n].x);
        p[n].y = fmaf(wv.y, z.y, p[n].y);
        p[n].z = fmaf(wv.z, z.z, p[n].z);
        p[n].w = fmaf(wv.w, z.w, p[n].w);
      }
    }
#pragma unroll
    for (int n = 0; n < 4; ++n)
      ash[w * 4 + n][lane] =
          fmaxf((p[n].x + p[n].y) + (p[n].z + p[n].w), 0.0f);
    __syncthreads();

    // layer 2
    float4 q[4];
#pragma unroll
    for (int n = 0; n < 4; ++n) q[n] = make_float4(0.f, 0.f, 0.f, 0.f);
#pragma unroll 4
    for (int k4 = 0; k4 < NHID / 4; ++k4) {
      float4 wv = w2v[k4][lane];
#pragma unroll
      for (int n = 0; n < 4; ++n) {
        float4 a = *(const float4*)&ash[w * 4 + n][k4 * 4];
        q[n].x = fmaf(wv.x, a.x, q[n].x);
        q[n].y = fmaf(wv.y, a.y, q[n].y);
        q[n].z = fmaf(wv.z, a.z, q[n].z);
        q[n].w = fmaf(wv.w, a.w, q[n].w);
      }
    }
#pragma unroll
    for (int n = 0; n < 4; ++n) {
      int node = nbase + n;
      if (node < N) {
        if (degv[n] > 0) {
          out[(long long)node * NHID + lane] =
              (q[n].x + q[n].y) + (q[n].z + q[n].w);
        } else {
          out[(long long)node * NHID + lane] = h[(long long)node * NHID + lane];
        }
      }
    }
    __syncthreads();  // protect zsh/ash WAR before next iteration's staging
  }
}

extern "C" void kernel_launch(void* const* d_in, const int* in_sizes, int n_in,
                              void* d_out, int out_size, void* d_ws, size_t ws_size,
                              hipStream_t stream) {
  const float* h  = (const float*)d_in[0];
  const float* nf = (const float*)d_in[1];
  const float* ef = (const float*)d_in[2];
  const int*   src = (const int*)d_in[3];
  const int*   dst = (const int*)d_in[4];
  const float* W1 = (const float*)d_in[5];
  const float* W2 = (const float*)d_in[6];
  float* out = (float*)d_out;

  int N = in_sizes[0] / NHID;  // h is [N, 64]
  int E = in_sizes[3];         // src is [E]

  // ws layout (4-byte elems):
  // counts[N] | starts[N+1] | cursors[N] | bsum[64] | boff[64] |
  // ssrc[E] | seid[E] | efsum[N*16] | hsum[N*64]
  int* counts  = (int*)d_ws;
  int* starts  = counts + N;
  int* cursors = starts + N + 1;
  int* bsum    = cursors + N;
  int* boff    = bsum + 64;
  int* ssrc    = boff + 64;
  int* seid    = ssrc + E;
  float* efsum = (float*)(seid + E);
  float* hsum  = efsum + (size_t)N * EDIM;

  hipMemsetAsync(counts, 0, (size_t)N * sizeof(int), stream);

  int eblocks = (E + 255) / 256;
  int nb = (N + SCHUNK - 1) / SCHUNK;  // 49 for N=50000 (must be <= 64)

  sse_hist<<<eblocks, 256, 0, stream>>>(dst, counts, E);
  sse_scan_part<<<nb, 256, 0, stream>>>(counts, bsum, N);
  sse_scan_top<<<1, 64, 0, stream>>>(bsum, boff, nb, &starts[N]);
  sse_scan_final<<<nb, 256, 0, stream>>>(counts, boff, starts, cursors, N);
  sse_build<<<eblocks, 256, 0, stream>>>(src, dst, cursors, ssrc, seid, E);

  int gblocks = (N + 3) / 4;
  sse_gather<<<gblocks, 256, 0, stream>>>(h, ef, starts, ssrc, seid,
                                          efsum, hsum, N);

  int ngroups = (N + 15) / 16;
  int nblocks = ngroups < 512 ? ngroups : 512;
  sse_node<<<nblocks, 256, 0, stream>>>(h, nf, efsum, hsum, starts, W1, W2,
                                        out, N, ngroups);
}